// Round 2
// baseline (326.205 us; speedup 1.0000x reference)
//
#include <hip/hip_runtime.h>

// RandCropResize v5: y-lerp hoisted into staging.
// B=64, C=3, H=W=512, fp32. One block per (b, oy). Staging loads the 2
// y-tap rows per channel (crop-span only), computes the y-interpolated row
// IN REGISTERS (once per source column, nx<=512 of them) and stores ONE
// fp32 row per channel to LDS. The per-pixel gather is then a single
// ds_read2_b32 + 2 VALU per channel (was 2 ds_read2 + 6 VALU): the kernel
// was VALU/LDS-pipe-bound (v4's fetch cut was time-neutral), so this
// roughly halves the dominant pipes. Arithmetic order (y-lerp then x-lerp)
// is identical to the reference.

#define BB 64
#define CC 3
#define HH 512
#define WW 512
#define NB (BB * HH)          // 32768 blocks
#define PITCH 516             // floats per LDS row; 516*4 % 16 == 0

__global__ __launch_bounds__(256) void rand_crop_resize_kernel(
    const float* __restrict__ img,
    const int* __restrict__ y1a, const int* __restrict__ y2a,
    const int* __restrict__ x1a, const int* __restrict__ x2a,
    float* __restrict__ out)
{
    __shared__ float s[3 * PITCH];   // one y-lerped row per channel

    // XCD swizzle: give XCD k a contiguous slice of 8 batches.
    const int r  = (blockIdx.x & 7) * (NB / 8) + (blockIdx.x >> 3);
    const int oy = r & (HH - 1);
    const int b  = r >> 9;

    const int Y1 = y1a[b], Y2 = y2a[b], X1 = x1a[b], X2 = x2a[b];

    // ---- y coords (uniform) ----
    const int ny_i = Y2 - Y1;
    float sy = ((float)oy + 0.5f) * (float)ny_i * (1.0f / 512.0f) - 0.5f;
    sy = fminf(fmaxf(sy, 0.0f), (float)ny_i - 1.0f);
    int iy0 = (int)sy;                       // sy >= 0, trunc == floor
    const int iy1 = min(iy0 + 1, ny_i - 1) + Y1;
    const float wy = sy - (float)iy0;
    iy0 += Y1;

    const int t = threadIdx.x;

    // ---- crop-span chunk range (uniform) ----
    const int nx_i = X2 - X1;
    const int c0   = X1 >> 2;                               // first float4 chunk
    const int c1   = min((X1 + nx_i) >> 2, (WW >> 2) - 1);  // last chunk <=127
    const int nch  = c1 - c0 + 1;                           // chunks/row <=128
    const int xoff = X1 - (c0 << 2);                        // = X1 & 3
    const int zi   = xoff + nx_i;                           // one-past slot <=515

    // zero the dead slot of each LDS row (read only when wx == 0; also stays
    // zero when X1+nx == 512, where a global load of it would be OOB)
    if (t < 3) s[t * PITCH + zi] = 0.0f;

    // ---- stage 3 y-lerped crop spans: 3 rows x <=128 chunks = <=384 slots ----
    const size_t base = (size_t)b * (size_t)(CC * HH * WW);
    #pragma unroll
    for (int i = 0; i < 2; ++i) {
        const int slot = t + 256 * i;        // i=0: 0..255, i=1: 256..383 (t<128)
        if (slot < 3 * 128) {
            const int c    = slot >> 7;      // channel 0..2
            const int lane = slot & 127;
            if (lane < nch) {
                const float* rowb = img + base + (size_t)(c * HH) * (size_t)WW;
                const float4 a = ((const float4*)(rowb + (size_t)iy0 * WW))[c0 + lane];
                const float4 q = ((const float4*)(rowb + (size_t)iy1 * WW))[c0 + lane];
                float4 v;
                v.x = a.x + (q.x - a.x) * wy;
                v.y = a.y + (q.y - a.y) * wy;
                v.z = a.z + (q.z - a.z) * wy;
                v.w = a.w + (q.w - a.w) * wy;
                ((float4*)(s + c * PITCH))[lane] = v;
            }
        }
    }
    __syncthreads();

    // ---- x lerp: 2 px/thread, coords shared across 3 channels ----
    const float nx    = (float)nx_i;
    const float nxm1f = nx - 1.0f;

    float2 res[3];
    #pragma unroll
    for (int k = 0; k < 2; ++k) {
        const int ox = 2 * t + k;
        float sx = ((float)ox + 0.5f) * nx * (1.0f / 512.0f) - 0.5f;
        sx = fminf(fmaxf(sx, 0.0f), nxm1f);
        const int   ix0 = (int)sx;           // sx >= 0, trunc == floor
        const float wx  = sx - (float)ix0;
        const int   ix  = xoff + ix0;        // local LDS index; ix+1 <= zi

        #pragma unroll
        for (int c = 0; c < 3; ++c) {
            const float* sc = s + c * PITCH;
            const float a = sc[ix];
            const float q = sc[ix + 1];      // fuses into ds_read2_b32
            const float v = a + (q - a) * wx;
            if (k == 0) res[c].x = v; else res[c].y = v;
        }
    }

    #pragma unroll
    for (int c = 0; c < 3; ++c) {
        float2* orow = (float2*)(out
            + ((size_t)(b * CC + c) * (size_t)HH + (size_t)oy) * (size_t)WW);
        orow[t] = res[c];
    }
}

extern "C" void kernel_launch(void* const* d_in, const int* in_sizes, int n_in,
                              void* d_out, int out_size, void* d_ws, size_t ws_size,
                              hipStream_t stream) {
    const float* img = (const float*)d_in[0];
    const int*   y1  = (const int*)d_in[1];
    const int*   y2  = (const int*)d_in[2];
    const int*   x1  = (const int*)d_in[3];
    const int*   x2  = (const int*)d_in[4];
    float*       out = (float*)d_out;

    dim3 grid(NB);      // 32768 blocks, one per (b, oy)
    dim3 block(256);
    hipLaunchKernelGGL(rand_crop_resize_kernel, grid, block, 0, stream,
                       img, y1, y2, x1, x2, out);
}